// Round 15
// baseline (343.537 us; speedup 1.0000x reference)
//
#include <hip/hip_runtime.h>
#include <hip/hip_bf16.h>
#include <stdint.h>

#define EMB   2048
#define TOK   2048
#define NH    32
#define NKV   8
#define HD    64
#define QKVN  3072   // 2048 q + 512 k + 512 v

typedef __attribute__((ext_vector_type(8))) short bf16x8;   // 8 bf16 = 4 VGPRs
typedef __attribute__((ext_vector_type(4))) float f32x4;
typedef __attribute__((ext_vector_type(16))) float f32x16;
typedef __attribute__((ext_vector_type(4))) unsigned int u32x4;

__device__ __forceinline__ void gld16(const void* g, void* l) {
  auto gp = reinterpret_cast<const int __attribute__((address_space(1)))*>(
      reinterpret_cast<uintptr_t>(g));
  auto lp = reinterpret_cast<int __attribute__((address_space(3)))*>(
      reinterpret_cast<uintptr_t>(l));
  __builtin_amdgcn_global_load_lds(gp, lp, 16, 0, 0);
}

__device__ __forceinline__ unsigned int cvtpk_bf16(float lo, float hi) {
  unsigned int r;
  asm("v_cvt_pk_bf16_f32 %0, %1, %2" : "=v"(r) : "v"(lo), "v"(hi));
  return r;
}
// v_permlane32_swap_b32 — only ever used with distinct-value operands (P-relayout).
__device__ __forceinline__ void pl32swap(unsigned int &a, unsigned int &b) {
  asm volatile("v_permlane32_swap_b32 %0, %1" : "+v"(a), "+v"(b));
}
__device__ __forceinline__ float fexp2(float x) {  // v_exp_f32 IS 2^x
  float r;
  asm("v_exp_f32 %0, %1" : "=v"(r) : "v"(x));
  return r;
}

// ---------------------------------------------------------------- cast fp32->bf16
__global__ void cast_all(const float* __restrict__ x,  const float* __restrict__ wq,
                         const float* __restrict__ wk, const float* __restrict__ wv,
                         const float* __restrict__ wo,
                         __hip_bfloat16* __restrict__ xb,
                         __hip_bfloat16* __restrict__ wc,
                         __hip_bfloat16* __restrict__ wob) {
  const size_t M4 = (size_t)4 * 1024 * 1024;
  const size_t M1 = (size_t)1024 * 1024;
  size_t i = ((size_t)blockIdx.x * 256 + threadIdx.x) * 4;
  const float* src;
  __hip_bfloat16* dst;
  if (i < M4)                    { src = x  + i;                 dst = xb  + i; }
  else if (i < 2*M4)             { src = wq + (i - M4);          dst = wc  + (i - M4); }
  else if (i < 2*M4 + M1)        { src = wk + (i - 2*M4);        dst = wc  + M4 + (i - 2*M4); }
  else if (i < 2*M4 + 2*M1)      { src = wv + (i - 2*M4 - M1);   dst = wc  + M4 + M1 + (i - 2*M4 - M1); }
  else                           { src = wo + (i - 2*M4 - 2*M1); dst = wob + (i - 2*M4 - 2*M1); }
  float4 v = *reinterpret_cast<const float4*>(src);
  dst[0] = __float2bfloat16(v.x);
  dst[1] = __float2bfloat16(v.y);
  dst[2] = __float2bfloat16(v.z);
  dst[3] = __float2bfloat16(v.w);
}

// ---------------------------------------------------------------- GEMM  C = A * B^T
// Counted-vmcnt 3-slot schedule (T3+T4), (row&7)<<4 XOR swizzle (T2), 8 waves.
template<int BN, typename OT>
__global__ __launch_bounds__(512) void gemm8(const __hip_bfloat16* __restrict__ A,
                                             const __hip_bfloat16* __restrict__ B,
                                             OT* __restrict__ C,
                                             int M, int N, int K) {
  constexpr int A_BYTES = 128 * 128;        // 16 KB
  constexpr int B_BYTES = BN * 128;
  constexpr int SLOT    = A_BYTES + B_BYTES;
  constexpr int CA = 2;
  constexpr int CB = BN / 64;
  constexpr int NR = BN / 64;
  extern __shared__ char lds[];             // 3 * SLOT

  const int nbc = N / BN;
  const int nwg = gridDim.x;
  int bid = blockIdx.x;
  bid = (bid & 7) * (nwg >> 3) + (bid >> 3);   // bijective XCD swizzle
  const int br = bid / nbc, bc = bid % nbc;

  const int tid  = threadIdx.x;
  const int w    = tid >> 6;
  const int lane = tid & 63;
  const int wr   = w >> 2, wc = w & 3;
  const int l15  = lane & 15, lg = lane >> 4;
  const int axor = (l15 & 7) << 4;

  const __hip_bfloat16* Ag = A + (size_t)br * 128 * K;
  const __hip_bfloat16* Bg = B + (size_t)bc * BN * K;

  const int srow = lane >> 3;
  const int scol = (((lane & 7) ^ srow) << 3);

  auto stageA = [&](char* slot, int kt) {
#pragma unroll
    for (int i = 0; i < CA; ++i) {
      const int c = w * CA + i;
      gld16(Ag + (size_t)(c * 8 + srow) * K + kt + scol, slot + c * 1024);
    }
  };
  auto stageB = [&](char* slot, int kt) {
#pragma unroll
    for (int i = 0; i < CB; ++i) {
      const int c = w * CB + i;
      gld16(Bg + (size_t)(c * 8 + srow) * K + kt + scol, slot + A_BYTES + c * 1024);
    }
  };
  auto ldA = [&](const char* sa, int m, int kk) {
    return *reinterpret_cast<const bf16x8*>(
        sa + (wr * 64 + m * 16 + l15) * 128 + ((kk * 64 + lg * 16) ^ axor));
  };
  auto ldB = [&](const char* sa, int n, int kk) {
    return *reinterpret_cast<const bf16x8*>(
        sa + A_BYTES + (wc * (BN / 4) + n * 16 + l15) * 128 + ((kk * 64 + lg * 16) ^ axor));
  };

  f32x4 acc[4][NR];
#pragma unroll
  for (int m = 0; m < 4; ++m)
#pragma unroll
    for (int n = 0; n < NR; ++n) acc[m][n] = (f32x4){0.f, 0.f, 0.f, 0.f};

  const int nt = K >> 6;

  stageA(lds, 0);         stageB(lds, 0);
  stageA(lds + SLOT, 64); stageB(lds + SLOT, 64);
  if constexpr (CA + CB == 4) asm volatile("s_waitcnt vmcnt(4)" ::: "memory");
  else                        asm volatile("s_waitcnt vmcnt(5)" ::: "memory");
  __builtin_amdgcn_s_barrier();

  int slc = 0, sls = 2;
  for (int t = 0; t < nt; ++t) {
    const char* sa = lds + slc * SLOT;
    char* stg = lds + sls * SLOT;
    const bool do_stage = (t + 2) < nt;
    const int kt2 = (t + 2) << 6;

    bf16x8 afr[2][2], bfr[NR][2];
#pragma unroll
    for (int m = 0; m < 2; ++m)
#pragma unroll
      for (int kk = 0; kk < 2; ++kk) afr[m][kk] = ldA(sa, m, kk);
#pragma unroll
    for (int n = 0; n < NR; ++n)
#pragma unroll
      for (int kk = 0; kk < 2; ++kk) bfr[n][kk] = ldB(sa, n, kk);
    if (do_stage) stageA(stg, kt2);
    __builtin_amdgcn_s_barrier();
    asm volatile("s_waitcnt lgkmcnt(0)" ::: "memory");
    __builtin_amdgcn_sched_barrier(0);
    __builtin_amdgcn_s_setprio(1);
#pragma unroll
    for (int m = 0; m < 2; ++m)
#pragma unroll
      for (int n = 0; n < NR; ++n)
#pragma unroll
        for (int kk = 0; kk < 2; ++kk)
          acc[m][n] = __builtin_amdgcn_mfma_f32_16x16x32_bf16(afr[m][kk], bfr[n][kk],
                                                              acc[m][n], 0, 0, 0);
    __builtin_amdgcn_s_setprio(0);
    __builtin_amdgcn_s_barrier();

#pragma unroll
    for (int m = 0; m < 2; ++m)
#pragma unroll
      for (int kk = 0; kk < 2; ++kk) afr[m][kk] = ldA(sa, 2 + m, kk);
    if (do_stage) stageB(stg, kt2);
    __builtin_amdgcn_s_barrier();
    asm volatile("s_waitcnt lgkmcnt(0)" ::: "memory");
    __builtin_amdgcn_sched_barrier(0);
    __builtin_amdgcn_s_setprio(1);
#pragma unroll
    for (int m = 0; m < 2; ++m)
#pragma unroll
      for (int n = 0; n < NR; ++n)
#pragma unroll
        for (int kk = 0; kk < 2; ++kk)
          acc[2 + m][n] = __builtin_amdgcn_mfma_f32_16x16x32_bf16(afr[m][kk], bfr[n][kk],
                                                                  acc[2 + m][n], 0, 0, 0);
    __builtin_amdgcn_s_setprio(0);
    if (t < nt - 2) {
      if constexpr (CA + CB == 4) asm volatile("s_waitcnt vmcnt(4)" ::: "memory");
      else                        asm volatile("s_waitcnt vmcnt(5)" ::: "memory");
    } else {
      asm volatile("s_waitcnt vmcnt(0)" ::: "memory");
    }
    __builtin_amdgcn_s_barrier();

    slc = (slc == 2) ? 0 : slc + 1;
    sls = (sls == 2) ? 0 : sls + 1;
  }

  const int row0 = br * 128 + wr * 64;
  const int col0 = bc * BN + wc * (BN / 4);
#pragma unroll
  for (int m = 0; m < 4; ++m)
#pragma unroll
    for (int n = 0; n < NR; ++n)
#pragma unroll
      for (int r = 0; r < 4; ++r) {
        const size_t off = (size_t)(row0 + m * 16 + lg * 4 + r) * N + col0 + n * 16 + l15;
        if constexpr (sizeof(OT) == 4) C[off] = acc[m][n][r];
        else                           C[off] = __float2bfloat16(acc[m][n][r]);
      }
}

// ---------------------------------------------------------------- RoPE + cast to tiled fragment layouts
#define QSCALE 0.1803368801111243f   // 0.125 * log2(e)

__device__ __forceinline__ size_t kq_idx(int tile_row, int t, int d) {
  return ((size_t)tile_row) * 2048 +
         ((((d >> 4) * 64) + (((d >> 3) & 1) * 32) + (t & 31)) << 3) + (d & 7);
}

__global__ void rope_cast(const __hip_bfloat16* __restrict__ qkv,
                          const float* __restrict__ cosT, const float* __restrict__ sinT,
                          __hip_bfloat16* __restrict__ Qf,
                          __hip_bfloat16* __restrict__ Kf,
                          __hip_bfloat16* __restrict__ Vf) {
  const int QP = TOK * NH * (HD / 2);   // 2,097,152
  const int KP = TOK * NKV * (HD / 2);  //   524,288
  int idx = blockIdx.x * 256 + threadIdx.x;
  if (idx < QP) {
    int d = idx & 31, h = (idx >> 5) & 31, t = idx >> 10;
    const __hip_bfloat16* row = qkv + (size_t)t * QKVN + h * 64;
    float x1 = __bfloat162float(row[d]), x2 = __bfloat162float(row[d + 32]);
    float o1 = (x1 * cosT[t * 64 + d]      - x2 * sinT[t * 64 + d])      * QSCALE;
    float o2 = (x2 * cosT[t * 64 + d + 32] + x1 * sinT[t * 64 + d + 32]) * QSCALE;
    const int tile_row = h * 64 + (t >> 5);
    Qf[kq_idx(tile_row, t, d)]      = __float2bfloat16(o1);
    Qf[kq_idx(tile_row, t, d + 32)] = __float2bfloat16(o2);
  } else if (idx < QP + KP) {
    int j = idx - QP;
    int d = j & 31, hk = (j >> 5) & 7, t = j >> 8;
    const __hip_bfloat16* row = qkv + (size_t)t * QKVN + 2048 + hk * 64;
    float x1 = __bfloat162float(row[d]), x2 = __bfloat162float(row[d + 32]);
    float o1 = x1 * cosT[t * 64 + d]      - x2 * sinT[t * 64 + d];
    float o2 = x2 * cosT[t * 64 + d + 32] + x1 * sinT[t * 64 + d + 32];
    const int tile_row = hk * 64 + (t >> 5);
    Kf[kq_idx(tile_row, t, d)]      = __float2bfloat16(o1);
    Kf[kq_idx(tile_row, t, d + 32)] = __float2bfloat16(o2);
  } else {
    int vj = idx - QP - KP;               // d fastest -> coalesced qkv reads
    int d = vj & 63, t = (vj >> 6) & (TOK - 1), hk = vj >> 17;
    const __hip_bfloat16 v = qkv[(size_t)t * QKVN + 2560 + hk * 64 + d];
    const size_t tb = ((size_t)hk * 64 + (t >> 5)) * 2048;
    const int c = (((t >> 4) & 1) * 128) + ((d >> 5) * 64) + (((t >> 3) & 1) * 32) + (d & 31);
    Vf[tb + (c << 3) + (t & 7)] = v;
  }
}

// ---------------------------------------------------------------- causal GQA flash attention
// Block-shared LDS-staged KV (R13-proven schedule, byte-identical loop).
// R14 delta: epilogue buffers (part_u, mlb) ALIAS the kv staging arena (kv is
// dead after the final loop barrier) -> LDS 68.6 KB -> 35.8 KB -> 4 blocks/CU
// (32 waves/CU) to fill the measured ~46% idle cycles.
#define MBIAS 10.0f
#define KV_BYTES   (2 * 16384)                     // 32 KB staging dbuf
#define PART_BYTES (8 * 32 * 33 * 4)               // 33792
#define SMEM_BYTES (PART_BYTES + 8 * 2 * 32 * 4)   // 35840 > KV_BYTES

// grid = 512: idx = (strip' << 3) | hk (hk fastest -> XCD affinity, strip desc)
__global__ __launch_bounds__(512, 8) void attnL(const __hip_bfloat16* __restrict__ Qf,
                                                const __hip_bfloat16* __restrict__ Kf,
                                                const __hip_bfloat16* __restrict__ Vf,
                                                __hip_bfloat16* __restrict__ ctx) {
  const int idx   = blockIdx.x;
  const int hk    = idx & 7;
  const int strip = 63 - (idx >> 3);
  const int tid   = threadIdx.x;
  const int w     = tid >> 6;                  // wave 0..7
  const int lane  = tid & 63;
  const int l31   = lane & 31, hi = lane >> 5;
  const int hq    = w & 3;                     // q-head within kv-group
  const int pr    = w >> 2;                    // kv parity 0/1
  const int h     = hk * 4 + hq;
  const int q0    = strip * 32;
  const int niter = (strip >> 1) + 1;          // ceil((strip+1)/2)

  __shared__ char smem[SMEM_BYTES];
  // loop phase: kv dbuf at smem[0..32K)       (epilogue arrays dead)
  // epilogue:   part_u/mlb at smem[0..35840)  (kv dead after final barrier)
  auto part_u = reinterpret_cast<unsigned int(*)[32][33]>(smem);      // [8][32][33]
  auto mlb    = reinterpret_cast<float(*)[2][32]>(smem + PART_BYTES); // [8][2][32]

  const __hip_bfloat16* Kt = Kf + (size_t)hk * 64 * 2048;
  const __hip_bfloat16* Vt = Vf + (size_t)hk * 64 * 2048;

  // Q frags (TC layout, coalesced)
  const __hip_bfloat16* Qp = Qf + ((size_t)h * 64 + strip) * 2048 + lane * 8;
  bf16x8 qf[4];
#pragma unroll
  for (int ks = 0; ks < 4; ++ks)
    qf[ks] = *reinterpret_cast<const bf16x8*>(Qp + ks * 512);

  f32x16 minit;
#pragma unroll
  for (int r = 0; r < 16; ++r) minit[r] = -MBIAS;

  f32x16 oa0, oa1;
#pragma unroll
  for (int r = 0; r < 16; ++r) { oa0[r] = 0.f; oa1[r] = 0.f; }
  float mb = 0.f, l = 0.f;

  // staging: wave w stages 2KB of the 16KB tile-pair. seg s = w>>1:
  // 0 = K[2i], 1 = K[2i+1], 2 = V[2i], 3 = V[2i+1]; half hh = w&1.
  const int sseg = w >> 1, shh = w & 1;
  const __hip_bfloat16* sbase = (sseg < 2) ? Kt : Vt;
  auto stage_pair = [&](int buf, int it) {
    const int tt = 2 * it + (sseg & 1);
    const int tc = (tt <= strip) ? tt : strip;       // clamp (uniform, harmless)
    const __hip_bfloat16* src = sbase + (size_t)tc * 2048 + shh * 1024 + lane * 8;
    char* dst = &smem[buf * 16384 + ((sseg >= 2) ? 8192 : 0) + (sseg & 1) * 4096 + shh * 2048];
    gld16(src,       dst);
    gld16(src + 512, dst + 1024);
  };

  stage_pair(0, 0);
  __syncthreads();                              // drains vmcnt: tiles 0/1 in LDS

  for (int it = 0; it < niter; ++it) {
    if (it + 1 < niter) stage_pair((it + 1) & 1, it + 1);

    const int t = 2 * it + pr;
    if (t <= strip) {                           // wave-uniform
      const char* kb = &smem[(it & 1) * 16384 + pr * 4096];
      const char* vb = &smem[(it & 1) * 16384 + 8192 + pr * 4096];
      const int lo = lane * 16;
      const bf16x8 k0 = *reinterpret_cast<const bf16x8*>(kb + lo);
      const bf16x8 k1 = *reinterpret_cast<const bf16x8*>(kb + 1024 + lo);
      const bf16x8 k2 = *reinterpret_cast<const bf16x8*>(kb + 2048 + lo);
      const bf16x8 k3 = *reinterpret_cast<const bf16x8*>(kb + 3072 + lo);

      __builtin_amdgcn_s_setprio(1);
      f32x16 st = __builtin_amdgcn_mfma_f32_32x32x16_bf16(k0, qf[0], minit, 0, 0, 0);
      st = __builtin_amdgcn_mfma_f32_32x32x16_bf16(k1, qf[1], st, 0, 0, 0);
      st = __builtin_amdgcn_mfma_f32_32x32x16_bf16(k2, qf[2], st, 0, 0, 0);
      st = __builtin_amdgcn_mfma_f32_32x32x16_bf16(k3, qf[3], st, 0, 0, 0);
      __builtin_amdgcn_s_setprio(0);

      float s[16];
#pragma unroll
      for (int r = 0; r < 16; ++r) s[r] = st[r];
      if (t == strip) {                         // diagonal: causal mask
#pragma unroll
        for (int r = 0; r < 16; ++r) {
          const int crow = (r & 3) + 8 * (r >> 2) + 4 * hi;
          s[r] = (crow <= l31) ? s[r] : -1e30f;
        }
      }
      float a0 = fmaxf(fmaxf(s[0], s[1]),  s[2]);
      float a1 = fmaxf(fmaxf(s[3], s[4]),  s[5]);
      float a2 = fmaxf(fmaxf(s[6], s[7]),  s[8]);
      float a3 = fmaxf(fmaxf(s[9], s[10]), s[11]);
      float a4 = fmaxf(fmaxf(s[12], s[13]), s[14]);
      float rmax = fmaxf(fmaxf(fmaxf(fmaxf(a0, a1), a2), fmaxf(a3, a4)), s[15]);
      rmax = fmaxf(rmax, __shfl_xor(rmax, 32));

      if (!__all(rmax <= mb + 8.0f)) {          // rescale: ~never taken w/ this data
        const float mnew = fmaxf(mb, rmax);
        const float resc = fexp2(mb - mnew);
        l *= resc;
#pragma unroll
        for (int r = 0; r < 16; ++r) { oa0[r] *= resc; oa1[r] *= resc; }
        mb = mnew;
      }

      float p[16];
      if (mb == 0.0f) {
#pragma unroll
        for (int r = 0; r < 16; ++r) p[r] = fexp2(s[r]);
      } else {
#pragma unroll
        for (int r = 0; r < 16; ++r) p[r] = fexp2(s[r] - mb);
      }
      float u0 = (p[0] + p[1]) + (p[2] + p[3]);
      float u1 = (p[4] + p[5]) + (p[6] + p[7]);
      float u2 = (p[8] + p[9]) + (p[10] + p[11]);
      float u3 = (p[12] + p[13]) + (p[14] + p[15]);
      float rsum = (u0 + u1) + (u2 + u3);
      rsum += __shfl_xor(rsum, 32);
      l += rsum;

      unsigned int wpk[8];
#pragma unroll
      for (int j = 0; j < 8; ++j) wpk[j] = cvtpk_bf16(p[2 * j], p[2 * j + 1]);

      const bf16x8 v00 = *reinterpret_cast<const bf16x8*>(vb + lo);
      const bf16x8 v10 = *reinterpret_cast<const bf16x8*>(vb + 1024 + lo);
      const bf16x8 v01 = *reinterpret_cast<const bf16x8*>(vb + 2048 + lo);
      const bf16x8 v11 = *reinterpret_cast<const bf16x8*>(vb + 3072 + lo);

      __builtin_amdgcn_s_setprio(1);
      {
        unsigned int x0 = wpk[0], y0 = wpk[2];  pl32swap(x0, y0);
        unsigned int x1 = wpk[1], y1 = wpk[3];  pl32swap(x1, y1);
        u32x4 pw; pw[0] = x0; pw[1] = x1; pw[2] = y0; pw[3] = y1;
        bf16x8 pf = *reinterpret_cast<bf16x8*>(&pw);
        oa0 = __builtin_amdgcn_mfma_f32_32x32x16_bf16(v00, pf, oa0, 0, 0, 0);
        oa1 = __builtin_amdgcn_mfma_f32_32x32x16_bf16(v10, pf, oa1, 0, 0, 0);
      }
      {
        unsigned int x0 = wpk[4], y0 = wpk[6];  pl32swap(x0, y0);
        unsigned int x1 = wpk[5], y1 = wpk[7];  pl32swap(x1, y1);
        u32x4 pw; pw[0] = x0; pw[1] = x1; pw[2] = y0; pw[3] = y1;
        bf16x8 pf = *reinterpret_cast<bf16x8*>(&pw);
        oa0 = __builtin_amdgcn_mfma_f32_32x32x16_bf16(v01, pf, oa0, 0, 0, 0);
        oa1 = __builtin_amdgcn_mfma_f32_32x32x16_bf16(v11, pf, oa1, 0, 0, 0);
      }
      __builtin_amdgcn_s_setprio(0);
    }
    __syncthreads();   // drains vmcnt (next pair staged) + all LDS reads done
  }
  // all kv reads complete for every wave (final barrier above) -> safe to alias

  // ---- partials to LDS (bf16-packed), overlaying the dead kv arena
#pragma unroll
  for (int r = 0; r < 16; ++r) {
    const int d0 = (r & 3) + 8 * (r >> 2) + 4 * hi;   // 0..31
    part_u[w][d0][l31] = cvtpk_bf16(oa0[r], oa1[r]);
  }
  if (hi == 0) { mlb[w][0][l31] = mb; mlb[w][1][l31] = l; }
  __syncthreads();

  // ---- merge the 2 parities per head + write ctx (coalesced: lanes span d)
  const int d  = tid & 63;
  const int g  = tid >> 6;                     // 0..7: head = g&3, q-half = g>>2
  const int mh = g & 3, qh = g >> 2;
  const int w0 = mh, w1 = mh + 4;
#pragma unroll
  for (int qq = 0; qq < 16; ++qq) {
    const int q = qh * 16 + qq;
    const float m0 = mlb[w0][0][q], m1 = mlb[w1][0][q];
    const float M = fmaxf(m0, m1);
    const float s0 = fexp2(m0 - M), s1 = fexp2(m1 - M);
    const float L = mlb[w0][1][q] * s0 + mlb[w1][1][q] * s1;
    const unsigned int u0 = part_u[w0][d & 31][q];
    const unsigned int u1 = part_u[w1][d & 31][q];
    const unsigned int b0 = (d < 32) ? (u0 << 16) : (u0 & 0xffff0000u);
    const unsigned int b1 = (d < 32) ? (u1 << 16) : (u1 & 0xffff0000u);
    const float p0 = __uint_as_float(b0), p1 = __uint_as_float(b1);
    ctx[(size_t)(q0 + q) * EMB + (hk * 4 + mh) * HD + d] =
        __float2bfloat16((p0 * s0 + p1 * s1) / L);
  }
}

// ---------------------------------------------------------------- launch
extern "C" void kernel_launch(void* const* d_in, const int* in_sizes, int n_in,
                              void* d_out, int out_size, void* d_ws, size_t ws_size,
                              hipStream_t stream) {
  const float* x    = (const float*)d_in[0];
  const float* cosT = (const float*)d_in[1];
  const float* sinT = (const float*)d_in[2];
  const float* Wq   = (const float*)d_in[3];
  const float* Wk   = (const float*)d_in[4];
  const float* Wv   = (const float*)d_in[5];
  const float* Wo   = (const float*)d_in[6];
  float* out = (float*)d_out;

  const size_t M4 = (size_t)4 * 1024 * 1024;
  const size_t M1 = (size_t)1024 * 1024;

  char* ws = (char*)d_ws;
  __hip_bfloat16* xb   = (__hip_bfloat16*)ws;
  __hip_bfloat16* Wc   = xb + M4;
  __hip_bfloat16* Wob  = Wc + (size_t)6 * M1;
  __hip_bfloat16* qkvb = Wob + M4;                    // bf16 qkv (12 MB)
  __hip_bfloat16* Qf   = qkvb + (size_t)TOK * QKVN;
  __hip_bfloat16* Kf   = Qf + (size_t)NH * TOK * HD;
  __hip_bfloat16* Vf   = Kf + (size_t)NKV * TOK * HD;
  __hip_bfloat16* ctxb = Vf + (size_t)NKV * HD * TOK;

  constexpr int SLOT192 = 128 * 128 + 192 * 128;
  constexpr int SLOT128 = 128 * 128 + 128 * 128;
  hipFuncSetAttribute(reinterpret_cast<const void*>(&gemm8<192, __hip_bfloat16>),
                      hipFuncAttributeMaxDynamicSharedMemorySize, 3 * SLOT192);
  hipFuncSetAttribute(reinterpret_cast<const void*>(&gemm8<128, float>),
                      hipFuncAttributeMaxDynamicSharedMemorySize, 3 * SLOT128);

  cast_all<<<14336, 256, 0, stream>>>(x, Wq, Wk, Wv, Wo, xb, Wc, Wob);

  // qkv = x @ Wqkv^T (M=2048, N=3072, K=2048), bf16 out: 256 blocks
  gemm8<192, __hip_bfloat16><<<256, 512, 3 * SLOT192, stream>>>(xb, Wc, qkvb,
                                                                TOK, QKVN, EMB);

  rope_cast<<<14336, 256, 0, stream>>>(qkvb, cosT, sinT, Qf, Kf, Vf);

  // causal GQA attention: LDS-staged, 4-head-shared KV, epilogue-aliased LDS
  attnL<<<64 * 8, 512, 0, stream>>>(Qf, Kf, Vf, ctxb);

  // out = ctx @ Wo^T (M=N=K=2048), fp32 out: 256 blocks
  gemm8<128, float><<<256, 512, 3 * SLOT128, stream>>>(ctxb, Wob, out, TOK, EMB, EMB);
}

// Round 16
// 119.019 us; speedup vs baseline: 2.8864x; 2.8864x over previous
//
#include <hip/hip_runtime.h>
#include <hip/hip_bf16.h>
#include <stdint.h>

#define EMB   2048
#define TOK   2048
#define NH    32
#define NKV   8
#define HD    64
#define QKVN  3072   // 2048 q + 512 k + 512 v

typedef __attribute__((ext_vector_type(8))) short bf16x8;   // 8 bf16 = 4 VGPRs
typedef __attribute__((ext_vector_type(4))) float f32x4;
typedef __attribute__((ext_vector_type(16))) float f32x16;
typedef __attribute__((ext_vector_type(4))) unsigned int u32x4;

__device__ __forceinline__ void gld16(const void* g, void* l) {
  auto gp = reinterpret_cast<const int __attribute__((address_space(1)))*>(
      reinterpret_cast<uintptr_t>(g));
  auto lp = reinterpret_cast<int __attribute__((address_space(3)))*>(
      reinterpret_cast<uintptr_t>(l));
  __builtin_amdgcn_global_load_lds(gp, lp, 16, 0, 0);
}

__device__ __forceinline__ unsigned int cvtpk_bf16(float lo, float hi) {
  unsigned int r;
  asm("v_cvt_pk_bf16_f32 %0, %1, %2" : "=v"(r) : "v"(lo), "v"(hi));
  return r;
}
// v_permlane32_swap_b32 — only ever used with distinct-value operands (P-relayout).
__device__ __forceinline__ void pl32swap(unsigned int &a, unsigned int &b) {
  asm volatile("v_permlane32_swap_b32 %0, %1" : "+v"(a), "+v"(b));
}
__device__ __forceinline__ float fexp2(float x) {  // v_exp_f32 IS 2^x
  float r;
  asm("v_exp_f32 %0, %1" : "=v"(r) : "v"(x));
  return r;
}

// ---------------------------------------------------------------- cast fp32->bf16
__global__ void cast_all(const float* __restrict__ x,  const float* __restrict__ wq,
                         const float* __restrict__ wk, const float* __restrict__ wv,
                         const float* __restrict__ wo,
                         __hip_bfloat16* __restrict__ xb,
                         __hip_bfloat16* __restrict__ wc,
                         __hip_bfloat16* __restrict__ wob) {
  const size_t M4 = (size_t)4 * 1024 * 1024;
  const size_t M1 = (size_t)1024 * 1024;
  size_t i = ((size_t)blockIdx.x * 256 + threadIdx.x) * 4;
  const float* src;
  __hip_bfloat16* dst;
  if (i < M4)                    { src = x  + i;                 dst = xb  + i; }
  else if (i < 2*M4)             { src = wq + (i - M4);          dst = wc  + (i - M4); }
  else if (i < 2*M4 + M1)        { src = wk + (i - 2*M4);        dst = wc  + M4 + (i - 2*M4); }
  else if (i < 2*M4 + 2*M1)      { src = wv + (i - 2*M4 - M1);   dst = wc  + M4 + M1 + (i - 2*M4 - M1); }
  else                           { src = wo + (i - 2*M4 - 2*M1); dst = wob + (i - 2*M4 - 2*M1); }
  float4 v = *reinterpret_cast<const float4*>(src);
  dst[0] = __float2bfloat16(v.x);
  dst[1] = __float2bfloat16(v.y);
  dst[2] = __float2bfloat16(v.z);
  dst[3] = __float2bfloat16(v.w);
}

// ---------------------------------------------------------------- GEMM  C = A * B^T
// Counted-vmcnt 3-slot schedule (T3+T4), (row&7)<<4 XOR swizzle (T2), 8 waves.
template<int BN, typename OT>
__global__ __launch_bounds__(512) void gemm8(const __hip_bfloat16* __restrict__ A,
                                             const __hip_bfloat16* __restrict__ B,
                                             OT* __restrict__ C,
                                             int M, int N, int K) {
  constexpr int A_BYTES = 128 * 128;        // 16 KB
  constexpr int B_BYTES = BN * 128;
  constexpr int SLOT    = A_BYTES + B_BYTES;
  constexpr int CA = 2;
  constexpr int CB = BN / 64;
  constexpr int NR = BN / 64;
  extern __shared__ char lds[];             // 3 * SLOT

  const int nbc = N / BN;
  const int nwg = gridDim.x;
  int bid = blockIdx.x;
  bid = (bid & 7) * (nwg >> 3) + (bid >> 3);   // bijective XCD swizzle
  const int br = bid / nbc, bc = bid % nbc;

  const int tid  = threadIdx.x;
  const int w    = tid >> 6;
  const int lane = tid & 63;
  const int wr   = w >> 2, wc = w & 3;
  const int l15  = lane & 15, lg = lane >> 4;
  const int axor = (l15 & 7) << 4;

  const __hip_bfloat16* Ag = A + (size_t)br * 128 * K;
  const __hip_bfloat16* Bg = B + (size_t)bc * BN * K;

  const int srow = lane >> 3;
  const int scol = (((lane & 7) ^ srow) << 3);

  auto stageA = [&](char* slot, int kt) {
#pragma unroll
    for (int i = 0; i < CA; ++i) {
      const int c = w * CA + i;
      gld16(Ag + (size_t)(c * 8 + srow) * K + kt + scol, slot + c * 1024);
    }
  };
  auto stageB = [&](char* slot, int kt) {
#pragma unroll
    for (int i = 0; i < CB; ++i) {
      const int c = w * CB + i;
      gld16(Bg + (size_t)(c * 8 + srow) * K + kt + scol, slot + A_BYTES + c * 1024);
    }
  };
  auto ldA = [&](const char* sa, int m, int kk) {
    return *reinterpret_cast<const bf16x8*>(
        sa + (wr * 64 + m * 16 + l15) * 128 + ((kk * 64 + lg * 16) ^ axor));
  };
  auto ldB = [&](const char* sa, int n, int kk) {
    return *reinterpret_cast<const bf16x8*>(
        sa + A_BYTES + (wc * (BN / 4) + n * 16 + l15) * 128 + ((kk * 64 + lg * 16) ^ axor));
  };

  f32x4 acc[4][NR];
#pragma unroll
  for (int m = 0; m < 4; ++m)
#pragma unroll
    for (int n = 0; n < NR; ++n) acc[m][n] = (f32x4){0.f, 0.f, 0.f, 0.f};

  const int nt = K >> 6;

  stageA(lds, 0);         stageB(lds, 0);
  stageA(lds + SLOT, 64); stageB(lds + SLOT, 64);
  if constexpr (CA + CB == 4) asm volatile("s_waitcnt vmcnt(4)" ::: "memory");
  else                        asm volatile("s_waitcnt vmcnt(5)" ::: "memory");
  __builtin_amdgcn_s_barrier();

  int slc = 0, sls = 2;
  for (int t = 0; t < nt; ++t) {
    const char* sa = lds + slc * SLOT;
    char* stg = lds + sls * SLOT;
    const bool do_stage = (t + 2) < nt;
    const int kt2 = (t + 2) << 6;

    bf16x8 afr[2][2], bfr[NR][2];
#pragma unroll
    for (int m = 0; m < 2; ++m)
#pragma unroll
      for (int kk = 0; kk < 2; ++kk) afr[m][kk] = ldA(sa, m, kk);
#pragma unroll
    for (int n = 0; n < NR; ++n)
#pragma unroll
      for (int kk = 0; kk < 2; ++kk) bfr[n][kk] = ldB(sa, n, kk);
    if (do_stage) stageA(stg, kt2);
    __builtin_amdgcn_s_barrier();
    asm volatile("s_waitcnt lgkmcnt(0)" ::: "memory");
    __builtin_amdgcn_sched_barrier(0);
    __builtin_amdgcn_s_setprio(1);
#pragma unroll
    for (int m = 0; m < 2; ++m)
#pragma unroll
      for (int n = 0; n < NR; ++n)
#pragma unroll
        for (int kk = 0; kk < 2; ++kk)
          acc[m][n] = __builtin_amdgcn_mfma_f32_16x16x32_bf16(afr[m][kk], bfr[n][kk],
                                                              acc[m][n], 0, 0, 0);
    __builtin_amdgcn_s_setprio(0);
    __builtin_amdgcn_s_barrier();

#pragma unroll
    for (int m = 0; m < 2; ++m)
#pragma unroll
      for (int kk = 0; kk < 2; ++kk) afr[m][kk] = ldA(sa, 2 + m, kk);
    if (do_stage) stageB(stg, kt2);
    __builtin_amdgcn_s_barrier();
    asm volatile("s_waitcnt lgkmcnt(0)" ::: "memory");
    __builtin_amdgcn_sched_barrier(0);
    __builtin_amdgcn_s_setprio(1);
#pragma unroll
    for (int m = 0; m < 2; ++m)
#pragma unroll
      for (int n = 0; n < NR; ++n)
#pragma unroll
        for (int kk = 0; kk < 2; ++kk)
          acc[2 + m][n] = __builtin_amdgcn_mfma_f32_16x16x32_bf16(afr[m][kk], bfr[n][kk],
                                                                  acc[2 + m][n], 0, 0, 0);
    __builtin_amdgcn_s_setprio(0);
    if (t < nt - 2) {
      if constexpr (CA + CB == 4) asm volatile("s_waitcnt vmcnt(4)" ::: "memory");
      else                        asm volatile("s_waitcnt vmcnt(5)" ::: "memory");
    } else {
      asm volatile("s_waitcnt vmcnt(0)" ::: "memory");
    }
    __builtin_amdgcn_s_barrier();

    slc = (slc == 2) ? 0 : slc + 1;
    sls = (sls == 2) ? 0 : sls + 1;
  }

  const int row0 = br * 128 + wr * 64;
  const int col0 = bc * BN + wc * (BN / 4);
#pragma unroll
  for (int m = 0; m < 4; ++m)
#pragma unroll
    for (int n = 0; n < NR; ++n)
#pragma unroll
      for (int r = 0; r < 4; ++r) {
        const size_t off = (size_t)(row0 + m * 16 + lg * 4 + r) * N + col0 + n * 16 + l15;
        if constexpr (sizeof(OT) == 4) C[off] = acc[m][n][r];
        else                           C[off] = __float2bfloat16(acc[m][n][r]);
      }
}

// ---------------------------------------------------------------- RoPE + cast to tiled fragment layouts
#define QSCALE 0.1803368801111243f   // 0.125 * log2(e)

__device__ __forceinline__ size_t kq_idx(int tile_row, int t, int d) {
  return ((size_t)tile_row) * 2048 +
         ((((d >> 4) * 64) + (((d >> 3) & 1) * 32) + (t & 31)) << 3) + (d & 7);
}

__global__ void rope_cast(const __hip_bfloat16* __restrict__ qkv,
                          const float* __restrict__ cosT, const float* __restrict__ sinT,
                          __hip_bfloat16* __restrict__ Qf,
                          __hip_bfloat16* __restrict__ Kf,
                          __hip_bfloat16* __restrict__ Vf) {
  const int QP = TOK * NH * (HD / 2);   // 2,097,152
  const int KP = TOK * NKV * (HD / 2);  //   524,288
  int idx = blockIdx.x * 256 + threadIdx.x;
  if (idx < QP) {
    int d = idx & 31, h = (idx >> 5) & 31, t = idx >> 10;
    const __hip_bfloat16* row = qkv + (size_t)t * QKVN + h * 64;
    float x1 = __bfloat162float(row[d]), x2 = __bfloat162float(row[d + 32]);
    float o1 = (x1 * cosT[t * 64 + d]      - x2 * sinT[t * 64 + d])      * QSCALE;
    float o2 = (x2 * cosT[t * 64 + d + 32] + x1 * sinT[t * 64 + d + 32]) * QSCALE;
    const int tile_row = h * 64 + (t >> 5);
    Qf[kq_idx(tile_row, t, d)]      = __float2bfloat16(o1);
    Qf[kq_idx(tile_row, t, d + 32)] = __float2bfloat16(o2);
  } else if (idx < QP + KP) {
    int j = idx - QP;
    int d = j & 31, hk = (j >> 5) & 7, t = j >> 8;
    const __hip_bfloat16* row = qkv + (size_t)t * QKVN + 2048 + hk * 64;
    float x1 = __bfloat162float(row[d]), x2 = __bfloat162float(row[d + 32]);
    float o1 = x1 * cosT[t * 64 + d]      - x2 * sinT[t * 64 + d];
    float o2 = x2 * cosT[t * 64 + d + 32] + x1 * sinT[t * 64 + d + 32];
    const int tile_row = hk * 64 + (t >> 5);
    Kf[kq_idx(tile_row, t, d)]      = __float2bfloat16(o1);
    Kf[kq_idx(tile_row, t, d + 32)] = __float2bfloat16(o2);
  } else {
    int vj = idx - QP - KP;               // d fastest -> coalesced qkv reads
    int d = vj & 63, t = (vj >> 6) & (TOK - 1), hk = vj >> 17;
    const __hip_bfloat16 v = qkv[(size_t)t * QKVN + 2560 + hk * 64 + d];
    const size_t tb = ((size_t)hk * 64 + (t >> 5)) * 2048;
    const int c = (((t >> 4) & 1) * 128) + ((d >> 5) * 64) + (((t >> 3) & 1) * 32) + (d & 31);
    Vf[tb + (c << 3) + (t & 7)] = v;
  }
}

// ---------------------------------------------------------------- causal GQA flash attention
// Block-shared LDS-staged KV (R13-proven schedule, byte-identical loop) with
// epilogue buffers aliasing the dead kv arena (LDS 35.8 KB -> 4 blocks/CU).
// launch_bounds (512,4) = R13's proven codegen (VGPR 52, no spill); R14's
// (512,8) pin forced VGPR->32 and spilled 770 MB to scratch (5.7x slowdown).
#define MBIAS 10.0f
#define PART_BYTES (8 * 32 * 33 * 4)               // 33792
#define SMEM_BYTES (PART_BYTES + 8 * 2 * 32 * 4)   // 35840 > 32 KB kv arena

// grid = 512: idx = (strip' << 3) | hk (hk fastest -> XCD affinity, strip desc)
__global__ __launch_bounds__(512, 4) void attnL(const __hip_bfloat16* __restrict__ Qf,
                                                const __hip_bfloat16* __restrict__ Kf,
                                                const __hip_bfloat16* __restrict__ Vf,
                                                __hip_bfloat16* __restrict__ ctx) {
  const int idx   = blockIdx.x;
  const int hk    = idx & 7;
  const int strip = 63 - (idx >> 3);
  const int tid   = threadIdx.x;
  const int w     = tid >> 6;                  // wave 0..7
  const int lane  = tid & 63;
  const int l31   = lane & 31, hi = lane >> 5;
  const int hq    = w & 3;                     // q-head within kv-group
  const int pr    = w >> 2;                    // kv parity 0/1
  const int h     = hk * 4 + hq;
  const int q0    = strip * 32;
  const int niter = (strip >> 1) + 1;          // ceil((strip+1)/2)

  __shared__ char smem[SMEM_BYTES];
  // loop phase: kv dbuf at smem[0..32K)       (epilogue arrays dead)
  // epilogue:   part_u/mlb at smem[0..35840)  (kv dead after final barrier)
  auto part_u = reinterpret_cast<unsigned int(*)[32][33]>(smem);      // [8][32][33]
  auto mlb    = reinterpret_cast<float(*)[2][32]>(smem + PART_BYTES); // [8][2][32]

  const __hip_bfloat16* Kt = Kf + (size_t)hk * 64 * 2048;
  const __hip_bfloat16* Vt = Vf + (size_t)hk * 64 * 2048;

  // Q frags (TC layout, coalesced)
  const __hip_bfloat16* Qp = Qf + ((size_t)h * 64 + strip) * 2048 + lane * 8;
  bf16x8 qf[4];
#pragma unroll
  for (int ks = 0; ks < 4; ++ks)
    qf[ks] = *reinterpret_cast<const bf16x8*>(Qp + ks * 512);

  f32x16 minit;
#pragma unroll
  for (int r = 0; r < 16; ++r) minit[r] = -MBIAS;

  f32x16 oa0, oa1;
#pragma unroll
  for (int r = 0; r < 16; ++r) { oa0[r] = 0.f; oa1[r] = 0.f; }
  float mb = 0.f, l = 0.f;

  // staging: wave w stages 2KB of the 16KB tile-pair. seg s = w>>1:
  // 0 = K[2i], 1 = K[2i+1], 2 = V[2i], 3 = V[2i+1]; half hh = w&1.
  const int sseg = w >> 1, shh = w & 1;
  const __hip_bfloat16* sbase = (sseg < 2) ? Kt : Vt;
  auto stage_pair = [&](int buf, int it) {
    const int tt = 2 * it + (sseg & 1);
    const int tc = (tt <= strip) ? tt : strip;       // clamp (uniform, harmless)
    const __hip_bfloat16* src = sbase + (size_t)tc * 2048 + shh * 1024 + lane * 8;
    char* dst = &smem[buf * 16384 + ((sseg >= 2) ? 8192 : 0) + (sseg & 1) * 4096 + shh * 2048];
    gld16(src,       dst);
    gld16(src + 512, dst + 1024);
  };

  stage_pair(0, 0);
  __syncthreads();                              // drains vmcnt: tiles 0/1 in LDS

  for (int it = 0; it < niter; ++it) {
    if (it + 1 < niter) stage_pair((it + 1) & 1, it + 1);

    const int t = 2 * it + pr;
    if (t <= strip) {                           // wave-uniform
      const char* kb = &smem[(it & 1) * 16384 + pr * 4096];
      const char* vb = &smem[(it & 1) * 16384 + 8192 + pr * 4096];
      const int lo = lane * 16;
      const bf16x8 k0 = *reinterpret_cast<const bf16x8*>(kb + lo);
      const bf16x8 k1 = *reinterpret_cast<const bf16x8*>(kb + 1024 + lo);
      const bf16x8 k2 = *reinterpret_cast<const bf16x8*>(kb + 2048 + lo);
      const bf16x8 k3 = *reinterpret_cast<const bf16x8*>(kb + 3072 + lo);

      __builtin_amdgcn_s_setprio(1);
      f32x16 st = __builtin_amdgcn_mfma_f32_32x32x16_bf16(k0, qf[0], minit, 0, 0, 0);
      st = __builtin_amdgcn_mfma_f32_32x32x16_bf16(k1, qf[1], st, 0, 0, 0);
      st = __builtin_amdgcn_mfma_f32_32x32x16_bf16(k2, qf[2], st, 0, 0, 0);
      st = __builtin_amdgcn_mfma_f32_32x32x16_bf16(k3, qf[3], st, 0, 0, 0);
      __builtin_amdgcn_s_setprio(0);

      float s[16];
#pragma unroll
      for (int r = 0; r < 16; ++r) s[r] = st[r];
      if (t == strip) {                         // diagonal: causal mask
#pragma unroll
        for (int r = 0; r < 16; ++r) {
          const int crow = (r & 3) + 8 * (r >> 2) + 4 * hi;
          s[r] = (crow <= l31) ? s[r] : -1e30f;
        }
      }
      float a0 = fmaxf(fmaxf(s[0], s[1]),  s[2]);
      float a1 = fmaxf(fmaxf(s[3], s[4]),  s[5]);
      float a2 = fmaxf(fmaxf(s[6], s[7]),  s[8]);
      float a3 = fmaxf(fmaxf(s[9], s[10]), s[11]);
      float a4 = fmaxf(fmaxf(s[12], s[13]), s[14]);
      float rmax = fmaxf(fmaxf(fmaxf(fmaxf(a0, a1), a2), fmaxf(a3, a4)), s[15]);
      rmax = fmaxf(rmax, __shfl_xor(rmax, 32));

      if (!__all(rmax <= mb + 8.0f)) {          // rescale: ~never taken w/ this data
        const float mnew = fmaxf(mb, rmax);
        const float resc = fexp2(mb - mnew);
        l *= resc;
#pragma unroll
        for (int r = 0; r < 16; ++r) { oa0[r] *= resc; oa1[r] *= resc; }
        mb = mnew;
      }

      float p[16];
      if (mb == 0.0f) {
#pragma unroll
        for (int r = 0; r < 16; ++r) p[r] = fexp2(s[r]);
      } else {
#pragma unroll
        for (int r = 0; r < 16; ++r) p[r] = fexp2(s[r] - mb);
      }
      float u0 = (p[0] + p[1]) + (p[2] + p[3]);
      float u1 = (p[4] + p[5]) + (p[6] + p[7]);
      float u2 = (p[8] + p[9]) + (p[10] + p[11]);
      float u3 = (p[12] + p[13]) + (p[14] + p[15]);
      float rsum = (u0 + u1) + (u2 + u3);
      rsum += __shfl_xor(rsum, 32);
      l += rsum;

      unsigned int wpk[8];
#pragma unroll
      for (int j = 0; j < 8; ++j) wpk[j] = cvtpk_bf16(p[2 * j], p[2 * j + 1]);

      const bf16x8 v00 = *reinterpret_cast<const bf16x8*>(vb + lo);
      const bf16x8 v10 = *reinterpret_cast<const bf16x8*>(vb + 1024 + lo);
      const bf16x8 v01 = *reinterpret_cast<const bf16x8*>(vb + 2048 + lo);
      const bf16x8 v11 = *reinterpret_cast<const bf16x8*>(vb + 3072 + lo);

      __builtin_amdgcn_s_setprio(1);
      {
        unsigned int x0 = wpk[0], y0 = wpk[2];  pl32swap(x0, y0);
        unsigned int x1 = wpk[1], y1 = wpk[3];  pl32swap(x1, y1);
        u32x4 pw; pw[0] = x0; pw[1] = x1; pw[2] = y0; pw[3] = y1;
        bf16x8 pf = *reinterpret_cast<bf16x8*>(&pw);
        oa0 = __builtin_amdgcn_mfma_f32_32x32x16_bf16(v00, pf, oa0, 0, 0, 0);
        oa1 = __builtin_amdgcn_mfma_f32_32x32x16_bf16(v10, pf, oa1, 0, 0, 0);
      }
      {
        unsigned int x0 = wpk[4], y0 = wpk[6];  pl32swap(x0, y0);
        unsigned int x1 = wpk[5], y1 = wpk[7];  pl32swap(x1, y1);
        u32x4 pw; pw[0] = x0; pw[1] = x1; pw[2] = y0; pw[3] = y1;
        bf16x8 pf = *reinterpret_cast<bf16x8*>(&pw);
        oa0 = __builtin_amdgcn_mfma_f32_32x32x16_bf16(v01, pf, oa0, 0, 0, 0);
        oa1 = __builtin_amdgcn_mfma_f32_32x32x16_bf16(v11, pf, oa1, 0, 0, 0);
      }
      __builtin_amdgcn_s_setprio(0);
    }
    __syncthreads();   // drains vmcnt (next pair staged) + all LDS reads done
  }
  // all kv reads complete for every wave (final barrier above) -> safe to alias

  // ---- partials to LDS (bf16-packed), overlaying the dead kv arena
#pragma unroll
  for (int r = 0; r < 16; ++r) {
    const int d0 = (r & 3) + 8 * (r >> 2) + 4 * hi;   // 0..31
    part_u[w][d0][l31] = cvtpk_bf16(oa0[r], oa1[r]);
  }
  if (hi == 0) { mlb[w][0][l31] = mb; mlb[w][1][l31] = l; }
  __syncthreads();

  // ---- merge the 2 parities per head + write ctx (coalesced: lanes span d)
  const int d  = tid & 63;
  const int g  = tid >> 6;                     // 0..7: head = g&3, q-half = g>>2
  const int mh = g & 3, qh = g >> 2;
  const int w0 = mh, w1 = mh + 4;
#pragma unroll
  for (int qq = 0; qq < 16; ++qq) {
    const int q = qh * 16 + qq;
    const float m0 = mlb[w0][0][q], m1 = mlb[w1][0][q];
    const float M = fmaxf(m0, m1);
    const float s0 = fexp2(m0 - M), s1 = fexp2(m1 - M);
    const float L = mlb[w0][1][q] * s0 + mlb[w1][1][q] * s1;
    const unsigned int u0 = part_u[w0][d & 31][q];
    const unsigned int u1 = part_u[w1][d & 31][q];
    const unsigned int b0 = (d < 32) ? (u0 << 16) : (u0 & 0xffff0000u);
    const unsigned int b1 = (d < 32) ? (u1 << 16) : (u1 & 0xffff0000u);
    const float p0 = __uint_as_float(b0), p1 = __uint_as_float(b1);
    ctx[(size_t)(q0 + q) * EMB + (hk * 4 + mh) * HD + d] =
        __float2bfloat16((p0 * s0 + p1 * s1) / L);
  }
}

// ---------------------------------------------------------------- launch
extern "C" void kernel_launch(void* const* d_in, const int* in_sizes, int n_in,
                              void* d_out, int out_size, void* d_ws, size_t ws_size,
                              hipStream_t stream) {
  const float* x    = (const float*)d_in[0];
  const float* cosT = (const float*)d_in[1];
  const float* sinT = (const float*)d_in[2];
  const float* Wq   = (const float*)d_in[3];
  const float* Wk   = (const float*)d_in[4];
  const float* Wv   = (const float*)d_in[5];
  const float* Wo   = (const float*)d_in[6];
  float* out = (float*)d_out;

  const size_t M4 = (size_t)4 * 1024 * 1024;
  const size_t M1 = (size_t)1024 * 1024;

  char* ws = (char*)d_ws;
  __hip_bfloat16* xb   = (__hip_bfloat16*)ws;
  __hip_bfloat16* Wc   = xb + M4;
  __hip_bfloat16* Wob  = Wc + (size_t)6 * M1;
  __hip_bfloat16* qkvb = Wob + M4;                    // bf16 qkv (12 MB)
  __hip_bfloat16* Qf   = qkvb + (size_t)TOK * QKVN;
  __hip_bfloat16* Kf   = Qf + (size_t)NH * TOK * HD;
  __hip_bfloat16* Vf   = Kf + (size_t)NKV * TOK * HD;
  __hip_bfloat16* ctxb = Vf + (size_t)NKV * HD * TOK;

  constexpr int SLOT192 = 128 * 128 + 192 * 128;
  constexpr int SLOT128 = 128 * 128 + 128 * 128;
  hipFuncSetAttribute(reinterpret_cast<const void*>(&gemm8<192, __hip_bfloat16>),
                      hipFuncAttributeMaxDynamicSharedMemorySize, 3 * SLOT192);
  hipFuncSetAttribute(reinterpret_cast<const void*>(&gemm8<128, float>),
                      hipFuncAttributeMaxDynamicSharedMemorySize, 3 * SLOT128);

  cast_all<<<14336, 256, 0, stream>>>(x, Wq, Wk, Wv, Wo, xb, Wc, Wob);

  // qkv = x @ Wqkv^T (M=2048, N=3072, K=2048), bf16 out: 256 blocks
  gemm8<192, __hip_bfloat16><<<256, 512, 3 * SLOT192, stream>>>(xb, Wc, qkvb,
                                                                TOK, QKVN, EMB);

  rope_cast<<<14336, 256, 0, stream>>>(qkvb, cosT, sinT, Qf, Kf, Vf);

  // causal GQA attention: LDS-staged, 4-head-shared KV, epilogue-aliased LDS
  attnL<<<64 * 8, 512, 0, stream>>>(Qf, Kf, Vf, ctxb);

  // out = ctx @ Wo^T (M=N=K=2048), fp32 out: 256 blocks
  gemm8<128, float><<<256, 512, 3 * SLOT128, stream>>>(ctxb, Wob, out, TOK, EMB, EMB);
}